// Round 14
// baseline (1334.260 us; speedup 1.0000x reference)
//
#include <hip/hip_runtime.h>

#define N_NODES 100000
#define N_EDGES 1600000
#define F 64

static_assert(N_NODES % 16 == 0, "node groups exact");
static_assert(N_EDGES % 16 == 0, "edge groups exact");

using short8  = __attribute__((ext_vector_type(8))) short;  // 8 bf16 (4 VGPRs)
using f32x4   = __attribute__((ext_vector_type(4))) float;
using uint32x4 = __attribute__((ext_vector_type(4))) unsigned;

#define MSTR 68   // uint stride for packed m buffer rows (16B multiple)
#define EWAVES 10 // waves per edge block (640 threads): 2 blocks/CU = 20 waves

#define NBLK_N ((N_NODES + 255) / 256)   // 391
#define NBLK_E (N_EDGES / 256)           // 6250

// silu with fast rcp (v_rcp_f32, ~1ulp) — output feeds bf16 anyway
__device__ __forceinline__ float silu_f(float v) {
    return v * __builtin_amdgcn_rcpf(1.0f + __expf(-v));
}

// f32 -> bf16 (RNE)
__device__ __forceinline__ short f2bf(float f) {
    unsigned u = __float_as_uint(f);
    unsigned r = (u + 0x7fffu + ((u >> 16) & 1u)) >> 16;
    return (short)r;
}
// bf16 bits -> f32
__device__ __forceinline__ float bf2f(short s) {
    return __uint_as_float(((unsigned)(unsigned short)s) << 16);
}

// packed pair f32 -> 2 x bf16 in one VALU op: [15:0]=bf16(a), [31:16]=bf16(b)
__device__ __forceinline__ unsigned cvt_pk_bf16(float a, float b) {
    unsigned r;
    asm("v_cvt_pk_bf16_f32 %0, %1, %2" : "=v"(r) : "v"(a), "v"(b));
    return r;
}

// split 8 f32 into hi/lo bf16 short8 fragments (cvt_pk pairs)
__device__ __forceinline__ void split8(const float* v, short8& h8, short8& l8) {
    unsigned hu[4], lu[4];
    #pragma unroll
    for (int p = 0; p < 4; ++p) {
        hu[p] = cvt_pk_bf16(v[2 * p], v[2 * p + 1]);
        const float r0 = v[2 * p]     - __uint_as_float(hu[p] << 16);
        const float r1 = v[2 * p + 1] - __uint_as_float(hu[p] & 0xffff0000u);
        lu[p] = cvt_pk_bf16(r0, r1);
    }
    h8 = __builtin_bit_cast(short8, (uint32x4){hu[0], hu[1], hu[2], hu[3]});
    l8 = __builtin_bit_cast(short8, (uint32x4){lu[0], lu[1], lu[2], lu[3]});
}

// ---------------- counting sort of edges by dst (once per launch) ----------

__global__ __launch_bounds__(256) void sort_zero(unsigned* __restrict__ cnt) {
    const int i = blockIdx.x * 256 + threadIdx.x;
    if (i < N_NODES) cnt[i] = 0u;
}

__global__ __launch_bounds__(256) void sort_hist(const int* __restrict__ dst,
                                                 unsigned* __restrict__ cnt) {
    const int e = blockIdx.x * 256 + threadIdx.x;
    atomicAdd(&cnt[dst[e]], 1u);
}

__global__ __launch_bounds__(256) void sort_psum(const unsigned* __restrict__ cnt,
                                                 unsigned* __restrict__ psum) {
    __shared__ unsigned ws[4];
    const int i = blockIdx.x * 256 + threadIdx.x;
    unsigned v = (i < N_NODES) ? cnt[i] : 0u;
    #pragma unroll
    for (int off = 1; off < 64; off <<= 1) v += __shfl_xor(v, off, 64);
    if ((threadIdx.x & 63) == 0) ws[threadIdx.x >> 6] = v;
    __syncthreads();
    if (threadIdx.x == 0) psum[blockIdx.x] = ws[0] + ws[1] + ws[2] + ws[3];
}

__global__ __launch_bounds__(64) void sort_scan(const unsigned* __restrict__ psum,
                                                unsigned* __restrict__ poff) {
    unsigned carry = 0u;
    const int t = threadIdx.x;
    for (int c = 0; c < NBLK_N; c += 64) {
        const int i = c + t;
        unsigned v = (i < NBLK_N) ? psum[i] : 0u;
        unsigned s = v;
        #pragma unroll
        for (int off = 1; off < 64; off <<= 1) {
            const unsigned u = __shfl_up(s, off, 64);
            if (t >= off) s += u;
        }
        if (i < NBLK_N) poff[i] = carry + s - v;
        carry += __shfl(s, 63, 64);
    }
}

__global__ __launch_bounds__(256) void sort_excl(const unsigned* __restrict__ cnt,
                                                 const unsigned* __restrict__ poff,
                                                 unsigned* __restrict__ cursor) {
    __shared__ unsigned ws[4];
    const int i = blockIdx.x * 256 + threadIdx.x;
    const unsigned v = (i < N_NODES) ? cnt[i] : 0u;
    unsigned s = v;
    #pragma unroll
    for (int off = 1; off < 64; off <<= 1) {
        const unsigned u = __shfl_up(s, off, 64);
        if ((threadIdx.x & 63) >= off) s += u;
    }
    if ((threadIdx.x & 63) == 63) ws[threadIdx.x >> 6] = s;
    __syncthreads();
    unsigned base = poff[blockIdx.x];
    const int w = threadIdx.x >> 6;
    #pragma unroll
    for (int k = 0; k < 3; ++k) if (k < w) base += ws[k];
    if (i < N_NODES) cursor[i] = base + s - v;
}

__global__ __launch_bounds__(256) void sort_scatter(const int* __restrict__ src,
                                                    const int* __restrict__ dst,
                                                    unsigned* __restrict__ cursor,
                                                    int* __restrict__ ssrc,
                                                    int* __restrict__ sdst) {
    const int e = blockIdx.x * 256 + threadIdx.x;
    const int d = dst[e];
    const unsigned p = atomicAdd(&cursor[d], 1u);
    ssrc[p] = src[e];
    sdst[p] = d;
}

// ---------------------------------------------------------------------------

// A = h @ ew1[0:64], B = h @ ew1[64:128] via split-bf16 MFMA (16 nodes/wave);
// also zero h_neigh / x_neigh for this layer. Weight staging parallel.
__global__ __launch_bounds__(256, 2) void node_pre(
    const float* __restrict__ h, const float* __restrict__ ew1,
    float* __restrict__ A, float* __restrict__ B,
    float* __restrict__ h_neigh, float* __restrict__ x_neigh)
{
    __shared__ short8 wHb[16][64];   // hi frags [t*2+kb][lane]; t 0-3 -> A, 4-7 -> B
    __shared__ short8 wLb[16][64];   // lo frags
    const int tid = threadIdx.x;
    const int w = tid >> 6, lane = tid & 63;
    const int col = lane & 15, quad = lane >> 4;
    #pragma unroll
    for (int tt = 0; tt < 2; ++tt) {
        const int t = w * 2 + tt;
        #pragma unroll
        for (int kb = 0; kb < 2; ++kb) {
            short8 hh, ll;
            #pragma unroll
            for (int j = 0; j < 8; ++j) {
                const int k = (t >> 2) * 64 + kb * 32 + quad * 8 + j;
                const float wv = ew1[k * 64 + (t & 3) * 16 + col];
                const short hs = f2bf(wv);
                hh[j] = hs; ll[j] = f2bf(wv - bf2f(hs));
            }
            wHb[t * 2 + kb][lane] = hh;
            wLb[t * 2 + kb][lane] = ll;
        }
    }
    __syncthreads();
    const int nwv = gridDim.x * 4;
    for (int g = blockIdx.x * 4 + w; g < N_NODES / 16; g += nwv) {
        asm volatile("" ::: "memory");
        const int n0 = g * 16;
        // h row of node (col) in A-frag order -> hi/lo fragments
        short8 ah[2], al[2];
        #pragma unroll
        for (int kb = 0; kb < 2; ++kb) {
            const f32x4* hp = (const f32x4*)(h + (size_t)(n0 + col) * 64 + kb * 32 + quad * 8);
            const f32x4 v0 = hp[0], v1 = hp[1];
            const float v[8] = {v0[0], v0[1], v0[2], v0[3], v1[0], v1[1], v1[2], v1[3]};
            split8(v, ah[kb], al[kb]);
        }
        #pragma unroll
        for (int t = 0; t < 8; ++t) {
            f32x4 z = {0.f, 0.f, 0.f, 0.f};
            #pragma unroll
            for (int kb = 0; kb < 2; ++kb) {
                const short8 Bh = wHb[t * 2 + kb][lane];
                const short8 Bl = wLb[t * 2 + kb][lane];
                z = __builtin_amdgcn_mfma_f32_16x16x32_bf16(ah[kb], Bh, z, 0, 0, 0);
                z = __builtin_amdgcn_mfma_f32_16x16x32_bf16(al[kb], Bh, z, 0, 0, 0);
                z = __builtin_amdgcn_mfma_f32_16x16x32_bf16(ah[kb], Bl, z, 0, 0, 0);
            }
            float* dstb = (t < 4) ? A : B;
            const int tt = t & 3;
            #pragma unroll
            for (int r = 0; r < 4; ++r)
                dstb[(size_t)(n0 + quad * 4 + r) * 64 + tt * 16 + col] = z[r];
        }
        // zero h_neigh (coalesced: lane owns 16 consecutive floats) + x_neigh
        {
            f32x4* hz = (f32x4*)(h_neigh + (size_t)n0 * 64 + lane * 16);
            const f32x4 zz = {0.f, 0.f, 0.f, 0.f};
            hz[0] = zz; hz[1] = zz; hz[2] = zz; hz[3] = zz;
        }
        if (lane < 48) x_neigh[n0 * 3 + lane] = 0.0f;
    }
}

// MFMA edge kernel over dst-sorted edges, split-bf16 (hi+lo) for ~f32 accuracy.
// 10-wave blocks (640 threads): LDS ~77.5 KB/block -> 2 blocks/CU = 20 waves
// (5 waves/SIMD; needs combined regs <= 102 — looser than the 8-wave path's
// 24-wave target which needed <= 85 and never materialized in R13).
// Full-width mbuf (R12 structure); per-t GEMM1 write-through + fused GEMM2
// keep only one f32x4 accumulator live. Grid 512 = exact 2/CU, single pass.
__global__ __launch_bounds__(640, 2) void edge_mfma(
    const float* __restrict__ A, const float* __restrict__ B,
    const float* __restrict__ x,
    const int* __restrict__ ssrc, const int* __restrict__ sdst,
    const float* __restrict__ rw,  const float* __restrict__ eb1,
    const float* __restrict__ ew2, const float* __restrict__ eb2,
    const float* __restrict__ cw1, const float* __restrict__ cb1,
    const float* __restrict__ cw2,
    float* __restrict__ h_neigh, float* __restrict__ x_neigh)
{
    __shared__ float rwb[F], eb1b[F];
    __shared__ short8 wEhb[8][64];            // hi(ew2) B-frags [t*2+kb][lane], 8 KB
    __shared__ short8 wElb[8][64];            // lo(ew2) B-frags, 8 KB
    __shared__ short8 wChb[8][64];            // hi(cw1) B-frags, 8 KB
    __shared__ short8 wClb[8][64];            // lo(cw1) B-frags, 8 KB
    __shared__ unsigned mbuf_s[EWAVES][16 * MSTR]; // packed (hi<<16|lo) of m
    __shared__ float cbuf_s[EWAVES][16];
    __shared__ float xbuf_s[EWAVES][48];      // xdn per (edge, comp)
    const int tid = threadIdx.x;
    const int w = tid >> 6, lane = tid & 63;
    const int col = lane & 15, quad = lane >> 4;
    if (tid < 64) rwb[tid] = rw[tid];
    else if (tid < 128) eb1b[tid - 64] = eb1[tid - 64];

    // weight staging: waves 0-7 each stage unit (t = w>>1, kb = w&1)
    if (w < 8) {
        const int t = w >> 1, kb = w & 1;
        short8 weh, wch, wel, wcl;
        #pragma unroll
        for (int j = 0; j < 8; ++j) {
            const int k = kb * 32 + quad * 8 + j;
            const float we = ew2[k * 64 + t * 16 + col];
            const float wc = cw1[k * 64 + t * 16 + col];
            const short weh_s = f2bf(we);
            const short wch_s = f2bf(wc);
            weh[j] = weh_s; wch[j] = wch_s;
            wel[j] = f2bf(we - bf2f(weh_s));
            wcl[j] = f2bf(wc - bf2f(wch_s));
        }
        wEhb[t * 2 + kb][lane] = weh;
        wElb[t * 2 + kb][lane] = wel;
        wChb[t * 2 + kb][lane] = wch;
        wClb[t * 2 + kb][lane] = wcl;
    }
    __syncthreads();

    unsigned* mbuf = &mbuf_s[w][0];
    float* cbuf = &cbuf_s[w][0];
    float* xbuf = &xbuf_s[w][0];

    float eb2c[4], cb1c[4], cw2c[4];
    #pragma unroll
    for (int t = 0; t < 4; ++t) {
        eb2c[t] = eb2[t * 16 + col];
        cb1c[t] = cb1[t * 16 + col];
        cw2c[t] = cw2[t * 16 + col];
    }

    const int eL = lane / 3;                 // coord lanes (<48): edge eL, comp cc
    const int cc = lane - eL * 3;
    const int nwv = gridDim.x * EWAVES;
    for (int g = blockIdx.x * EWAVES + w; g < N_EDGES / 16; g += nwv) {
        // compiler barrier: keep LDS-resident weights in LDS (no LICM re-hoist)
        asm volatile("" ::: "memory");

        const int e0 = g * 16;
        const int sv = ssrc[e0 + col];       // edge (col) indices, replicated per quad
        const int dv = sdst[e0 + col];       // sorted: non-decreasing over col

        // gathers directly in A-frag order
        const f32x4* ap = (const f32x4*)(A + (size_t)sv * 64);
        const f32x4* bp = (const f32x4*)(B + (size_t)dv * 64);
        f32x4 ag[4], bg[4];
        ag[0] = ap[quad * 2];     ag[1] = ap[quad * 2 + 1];
        ag[2] = ap[8 + quad * 2]; ag[3] = ap[8 + quad * 2 + 1];
        bg[0] = bp[quad * 2];     bg[1] = bp[quad * 2 + 1];
        bg[2] = bp[8 + quad * 2]; bg[3] = bp[8 + quad * 2 + 1];

        // radial + normalized diff (lanes 0..47 own (edge, comp))
        const int ms = __shfl(sv, eL, 64);
        const int md = __shfl(dv, eL, 64);
        float xs = 0.0f;
        if (lane < 48) xs = x[ms * 3 + cc] - x[md * 3 + cc];
        const float xx = xs * xs;
        const int b3 = col * 3;
        const float radE = __shfl(xx, b3, 64) + __shfl(xx, b3 + 1, 64)
                         + __shfl(xx, b3 + 2, 64);        // radial of edge (col)
        const float rad_e = __shfl(radE, eL, 64);
        const float xdn = xs * __builtin_amdgcn_rcpf(sqrtf(rad_e) + 1e-30f);
        if (lane < 48) xbuf[lane] = xdn;

        // m1 = silu(A[src]+B[dst]+rad*rw+eb1) -> hi/lo A-frags (cvt_pk pairs)
        short8 m1h[2], m1l[2];
        const float* agf = (const float*)ag;
        const float* bgf = (const float*)bg;
        #pragma unroll
        for (int kb = 0; kb < 2; ++kb) {
            float v[8];
            #pragma unroll
            for (int j = 0; j < 8; ++j) {
                const int k = kb * 32 + quad * 8 + j;
                const float pre = agf[kb * 8 + j] + bgf[kb * 8 + j]
                                + radE * rwb[k] + eb1b[k];
                v[j] = silu_f(pre);
            }
            split8(v, m1h[kb], m1l[kb]);
        }

        // GEMM1: m = silu(m1 @ ew2 + eb2) -> packed mbuf (one acc live per t)
        #pragma unroll
        for (int t = 0; t < 4; ++t) {
            f32x4 z = {0.f, 0.f, 0.f, 0.f};
            #pragma unroll
            for (int kb = 0; kb < 2; ++kb) {
                const short8 Eh = wEhb[t * 2 + kb][lane];
                const short8 El = wElb[t * 2 + kb][lane];
                z = __builtin_amdgcn_mfma_f32_16x16x32_bf16(m1h[kb], Eh, z, 0, 0, 0);
                z = __builtin_amdgcn_mfma_f32_16x16x32_bf16(m1l[kb], Eh, z, 0, 0, 0);
                z = __builtin_amdgcn_mfma_f32_16x16x32_bf16(m1h[kb], El, z, 0, 0, 0);
            }
            float v[4];
            #pragma unroll
            for (int r = 0; r < 4; ++r) v[r] = silu_f(z[r] + eb2c[t]);
            #pragma unroll
            for (int p = 0; p < 2; ++p) {
                const unsigned hu = cvt_pk_bf16(v[2 * p], v[2 * p + 1]);
                const float r0 = v[2 * p]     - __uint_as_float(hu << 16);
                const float r1 = v[2 * p + 1] - __uint_as_float(hu & 0xffff0000u);
                const unsigned lu = cvt_pk_bf16(r0, r1);
                const unsigned w0 = (hu << 16) | (lu & 0xffffu);
                const unsigned w1 = (hu & 0xffff0000u) | (lu >> 16);
                mbuf[(quad * 4 + 2 * p)     * MSTR + t * 16 + col] = w0;
                mbuf[(quad * 4 + 2 * p + 1) * MSTR + t * 16 + col] = w1;
            }
        }

        // segmented reduction of m over sorted dst runs: lane = feature.
        // readlane -> SGPR: boundary compares and branches are SCALAR.
        {
            float hacc = 0.0f;
            int prev = __builtin_amdgcn_readlane(dv, 0);
            bool first = true;
            #pragma unroll
            for (int e = 0; e < 16; ++e) {
                const int de = __builtin_amdgcn_readlane(dv, e);
                if (de != prev) {
                    float* p = &h_neigh[(size_t)prev * 64 + lane];
                    if (first) atomicAdd(p, hacc); else *p = hacc;
                    first = false;
                    hacc = 0.0f;
                    prev = de;
                }
                const unsigned u = mbuf[e * MSTR + lane];
                hacc += bf2f((short)(u >> 16)) + bf2f((short)(u & 0xffffu));
            }
            atomicAdd(&h_neigh[(size_t)prev * 64 + lane], hacc);
        }

        // m as hi/lo A-frags (LDS round trip = C/D -> A layout transform)
        short8 mh[2], ml[2];
        #pragma unroll
        for (int kb = 0; kb < 2; ++kb) {
            const unsigned* mp = &mbuf[col * MSTR + kb * 32 + quad * 8];
            short8 h8, l8;
            #pragma unroll
            for (int j = 0; j < 8; ++j) {
                const unsigned u = mp[j];
                h8[j] = (short)(u >> 16);
                l8[j] = (short)(u & 0xffffu);
            }
            mh[kb] = h8; ml[kb] = l8;
        }

        // GEMM2 fused with c-reduction: one accumulator live at a time
        float part[4] = {0.f, 0.f, 0.f, 0.f};
        #pragma unroll
        for (int t = 0; t < 4; ++t) {
            f32x4 z = {0.f, 0.f, 0.f, 0.f};
            #pragma unroll
            for (int kb = 0; kb < 2; ++kb) {
                const short8 Ch = wChb[t * 2 + kb][lane];
                const short8 Cl = wClb[t * 2 + kb][lane];
                z = __builtin_amdgcn_mfma_f32_16x16x32_bf16(mh[kb], Ch, z, 0, 0, 0);
                z = __builtin_amdgcn_mfma_f32_16x16x32_bf16(ml[kb], Ch, z, 0, 0, 0);
                z = __builtin_amdgcn_mfma_f32_16x16x32_bf16(mh[kb], Cl, z, 0, 0, 0);
            }
            #pragma unroll
            for (int r = 0; r < 4; ++r)
                part[r] = fmaf(silu_f(z[r] + cb1c[t]), cw2c[t], part[r]);
        }
        #pragma unroll
        for (int off = 8; off >= 1; off >>= 1)
            #pragma unroll
            for (int r = 0; r < 4; ++r)
                part[r] += __shfl_xor(part[r], off, 64);

        if (col == 0) {
            f32x4 cv = {part[0], part[1], part[2], part[3]};
            *(f32x4*)&cbuf[quad * 4] = cv;
        }

        // segmented x_neigh scatter: 3 lanes, scalar run boundaries (readlane)
        if (lane < 3) {
            float xacc = 0.0f;
            int prev = __builtin_amdgcn_readlane(dv, 0);
            bool first = true;
            #pragma unroll
            for (int e = 0; e < 16; ++e) {
                const int de = __builtin_amdgcn_readlane(dv, e);
                if (de != prev) {
                    float* p = &x_neigh[(size_t)prev * 3 + lane];
                    if (first) atomicAdd(p, xacc); else *p = xacc;
                    first = false;
                    xacc = 0.0f;
                    prev = de;
                }
                xacc = fmaf(cbuf[e], xbuf[e * 3 + lane], xacc);
            }
            atomicAdd(&x_neigh[(size_t)prev * 3 + lane], xacc);
        }
    }
}

// h_new = silu([h,h_neigh] @ nw1 + nb1) @ nw2 + nb2;  x_new = x + x_neigh.
// Split-bf16 MFMA, 16 nodes/wave; weight staging parallel across 4 waves.
__global__ __launch_bounds__(256, 2) void node_post(
    const float* __restrict__ h, const float* __restrict__ hng,
    const float* __restrict__ nw1, const float* __restrict__ nb1,
    const float* __restrict__ nw2, const float* __restrict__ nb2,
    const float* __restrict__ x_in, const float* __restrict__ xng,
    float* __restrict__ h_out, float* __restrict__ x_out)
{
    __shared__ short8 w1h[16][64], w1l[16][64];  // nw1 frags [t*4+kb][lane], 32 KB
    __shared__ short8 w2h[8][64],  w2l[8][64];   // nw2 frags [t*2+kb][lane], 16 KB
    __shared__ unsigned mbuf_s[4][16 * MSTR];    // per-wave packed intermediate
    const int tid = threadIdx.x;
    const int w = tid >> 6, lane = tid & 63;
    const int col = lane & 15, quad = lane >> 4;
    {
        const int t = w;  // wave w stages t = w for both weight sets
        #pragma unroll
        for (int kb = 0; kb < 4; ++kb) {
            short8 hh, ll;
            #pragma unroll
            for (int j = 0; j < 8; ++j) {
                const int k = kb * 32 + quad * 8 + j;
                const float wv = nw1[k * 64 + t * 16 + col];
                const short hs = f2bf(wv);
                hh[j] = hs; ll[j] = f2bf(wv - bf2f(hs));
            }
            w1h[t * 4 + kb][lane] = hh;
            w1l[t * 4 + kb][lane] = ll;
        }
        #pragma unroll
        for (int kb = 0; kb < 2; ++kb) {
            short8 hh, ll;
            #pragma unroll
            for (int j = 0; j < 8; ++j) {
                const int k = kb * 32 + quad * 8 + j;
                const float wv = nw2[k * 64 + t * 16 + col];
                const short hs = f2bf(wv);
                hh[j] = hs; ll[j] = f2bf(wv - bf2f(hs));
            }
            w2h[t * 2 + kb][lane] = hh;
            w2l[t * 2 + kb][lane] = ll;
        }
    }
    __syncthreads();

    unsigned* mbuf = &mbuf_s[w][0];
    float b1c[4], b2c[4];
    #pragma unroll
    for (int t = 0; t < 4; ++t) {
        b1c[t] = nb1[t * 16 + col];
        b2c[t] = nb2[t * 16 + col];
    }

    const int nwv = gridDim.x * 4;
    for (int g = blockIdx.x * 4 + w; g < N_NODES / 16; g += nwv) {
        asm volatile("" ::: "memory");
        const int n0 = g * 16;
        // A-frags over K=128: kb 0,1 from h row; kb 2,3 from hng row
        short8 ah[4], al[4];
        #pragma unroll
        for (int kb = 0; kb < 4; ++kb) {
            const float* base = (kb < 2) ? h : hng;
            const f32x4* hp = (const f32x4*)(base + (size_t)(n0 + col) * 64
                                             + (kb & 1) * 32 + quad * 8);
            const f32x4 v0 = hp[0], v1 = hp[1];
            const float v[8] = {v0[0], v0[1], v0[2], v0[3], v1[0], v1[1], v1[2], v1[3]};
            split8(v, ah[kb], al[kb]);
        }

        // GEMM1: t_pre = [h,hng] @ nw1 + nb1; silu -> packed mbuf
        #pragma unroll
        for (int t = 0; t < 4; ++t) {
            f32x4 z = {b1c[t], b1c[t], b1c[t], b1c[t]};
            #pragma unroll
            for (int kb = 0; kb < 4; ++kb) {
                const short8 Bh = w1h[t * 4 + kb][lane];
                const short8 Bl = w1l[t * 4 + kb][lane];
                z = __builtin_amdgcn_mfma_f32_16x16x32_bf16(ah[kb], Bh, z, 0, 0, 0);
                z = __builtin_amdgcn_mfma_f32_16x16x32_bf16(al[kb], Bh, z, 0, 0, 0);
                z = __builtin_amdgcn_mfma_f32_16x16x32_bf16(ah[kb], Bl, z, 0, 0, 0);
            }
            float v[4];
            #pragma unroll
            for (int r = 0; r < 4; ++r) v[r] = silu_f(z[r]);
            #pragma unroll
            for (int p = 0; p < 2; ++p) {
                const unsigned hu = cvt_pk_bf16(v[2 * p], v[2 * p + 1]);
                const float r0 = v[2 * p]     - __uint_as_float(hu << 16);
                const float r1 = v[2 * p + 1] - __uint_as_float(hu & 0xffff0000u);
                const unsigned lu = cvt_pk_bf16(r0, r1);
                const unsigned w0 = (hu << 16) | (lu & 0xffffu);
                const unsigned w1 = (hu & 0xffff0000u) | (lu >> 16);
                mbuf[(quad * 4 + 2 * p)     * MSTR + t * 16 + col] = w0;
                mbuf[(quad * 4 + 2 * p + 1) * MSTR + t * 16 + col] = w1;
            }
        }

        // reload intermediate as hi/lo A-frags (C/D -> A layout transform)
        short8 mh[2], ml[2];
        #pragma unroll
        for (int kb = 0; kb < 2; ++kb) {
            const unsigned* mp = &mbuf[col * MSTR + kb * 32 + quad * 8];
            short8 h8, l8;
            #pragma unroll
            for (int j = 0; j < 8; ++j) {
                const unsigned u = mp[j];
                h8[j] = (short)(u >> 16);
                l8[j] = (short)(u & 0xffffu);
            }
            mh[kb] = h8; ml[kb] = l8;
        }

        // GEMM2: h_new = t @ nw2 + nb2
        #pragma unroll
        for (int t = 0; t < 4; ++t) {
            f32x4 z = {b2c[t], b2c[t], b2c[t], b2c[t]};
            #pragma unroll
            for (int kb = 0; kb < 2; ++kb) {
                const short8 Bh = w2h[t * 2 + kb][lane];
                const short8 Bl = w2l[t * 2 + kb][lane];
                z = __builtin_amdgcn_mfma_f32_16x16x32_bf16(mh[kb], Bh, z, 0, 0, 0);
                z = __builtin_amdgcn_mfma_f32_16x16x32_bf16(ml[kb], Bh, z, 0, 0, 0);
                z = __builtin_amdgcn_mfma_f32_16x16x32_bf16(mh[kb], Bl, z, 0, 0, 0);
            }
            #pragma unroll
            for (int r = 0; r < 4; ++r)
                h_out[(size_t)(n0 + quad * 4 + r) * 64 + t * 16 + col] = z[r];
        }

        // x update for these 16 nodes (48 components)
        if (lane < 48) x_out[n0 * 3 + lane] = x_in[n0 * 3 + lane] + xng[n0 * 3 + lane];
    }
}

// final layer: only x_out = x + x_neigh (h_new of layer 3 is never read)
__global__ __launch_bounds__(256) void x_finish(
    const float* __restrict__ x_in, const float* __restrict__ xng,
    float* __restrict__ x_out)
{
    const int i = blockIdx.x * 256 + threadIdx.x;
    if (i < N_NODES * 3) x_out[i] = x_in[i] + xng[i];
}

extern "C" void kernel_launch(void* const* d_in, const int* in_sizes, int n_in,
                              void* d_out, int out_size, void* d_ws, size_t ws_size,
                              hipStream_t stream) {
    const float* h_in0 = (const float*)d_in[0];
    const float* x_in0 = (const float*)d_in[1];
    const int*   src   = (const int*)d_in[2];
    const int*   dst   = (const int*)d_in[3];
    const float* ew1   = (const float*)d_in[4];
    const float* eb1   = (const float*)d_in[5];
    const float* ew2   = (const float*)d_in[6];
    const float* eb2   = (const float*)d_in[7];
    const float* nw1   = (const float*)d_in[8];
    const float* nb1   = (const float*)d_in[9];
    const float* nw2   = (const float*)d_in[10];
    const float* nb2   = (const float*)d_in[11];
    const float* cw1   = (const float*)d_in[12];
    const float* cb1   = (const float*)d_in[13];
    const float* cw2   = (const float*)d_in[14];
    float* out = (float*)d_out;

    const size_t NF = (size_t)N_NODES * F;
    float* A   = (float*)d_ws;       // [N,64]
    float* Bm  = A + NF;             // [N,64]
    float* hng = Bm + NF;            // h_neigh [N,64]
    float* h0  = hng + NF;           // h ping  [N,64]
    float* h1  = h0 + NF;            // h pong  [N,64]
    float* xw  = h1 + NF;            // x       [N,3]
    float* xng = xw + (size_t)N_NODES * 3;  // x_neigh [N,3]
    unsigned* cnt    = (unsigned*)(xng + (size_t)N_NODES * 3);  // [N]
    unsigned* cursor = cnt + N_NODES;                           // [N]
    unsigned* psum   = cursor + N_NODES;                        // [NBLK_N]
    unsigned* poff   = psum + NBLK_N;                           // [NBLK_N]
    int* ssrc = (int*)(poff + NBLK_N);                          // [E]
    int* sdst = ssrc + N_EDGES;                                 // [E]

    // counting sort of edges by dst — once per launch, shared by all 4 layers
    sort_zero<<<NBLK_N, 256, 0, stream>>>(cnt);
    sort_hist<<<NBLK_E, 256, 0, stream>>>(dst, cnt);
    sort_psum<<<NBLK_N, 256, 0, stream>>>(cnt, psum);
    sort_scan<<<1, 64, 0, stream>>>(psum, poff);
    sort_excl<<<NBLK_N, 256, 0, stream>>>(cnt, poff, cursor);
    sort_scatter<<<NBLK_E, 256, 0, stream>>>(src, dst, cursor, ssrc, sdst);

    for (int d = 0; d < 4; ++d) {
        const float* hcur = (d == 0) ? h_in0 : ((d & 1) ? h0 : h1);
        float* hout = (d & 1) ? h1 : h0;
        const float* xcur = (d == 0) ? x_in0 : xw;
        node_pre<<<512, 256, 0, stream>>>(hcur, ew1 + (size_t)d * 129 * F,
                                          A, Bm, hng, xng);
        edge_mfma<<<512, 640, 0, stream>>>(A, Bm, xcur, ssrc, sdst,
            ew1 + (size_t)d * 129 * F + 128 * F, eb1 + d * F,
            ew2 + (size_t)d * F * F, eb2 + d * F,
            cw1 + (size_t)d * F * F, cb1 + d * F, cw2 + d * F,
            hng, xng);
        if (d < 3) {
            node_post<<<512, 256, 0, stream>>>(hcur, hng,
                nw1 + (size_t)d * 2 * F * F, nb1 + d * F,
                nw2 + (size_t)d * F * F, nb2 + d * F,
                xcur, xng, hout, xw);
        } else {
            x_finish<<<(N_NODES * 3 + 255) / 256, 256, 0, stream>>>(xcur, xng, out);
        }
    }
}

// Round 15
// 1163.270 us; speedup vs baseline: 1.1470x; 1.1470x over previous
//
#include <hip/hip_runtime.h>

#define N_NODES 100000
#define N_EDGES 1600000
#define F 64

static_assert(N_NODES % 16 == 0, "node groups exact");
static_assert(N_EDGES % 16 == 0, "edge groups exact");

using short8  = __attribute__((ext_vector_type(8))) short;  // 8 bf16 (4 VGPRs)
using f32x4   = __attribute__((ext_vector_type(4))) float;
using uint32x4 = __attribute__((ext_vector_type(4))) unsigned;

#define MSTR 68   // uint stride for packed m buffer rows (16B multiple)
#define EWAVES 8  // waves per edge block (512 threads): 2 blocks/CU = 16 waves

#define NBLK_N ((N_NODES + 255) / 256)   // 391
#define NBLK_E (N_EDGES / 256)           // 6250

// silu with fast rcp (v_rcp_f32, ~1ulp) — output feeds bf16 anyway
__device__ __forceinline__ float silu_f(float v) {
    return v * __builtin_amdgcn_rcpf(1.0f + __expf(-v));
}

// f32 -> bf16 (RNE)
__device__ __forceinline__ short f2bf(float f) {
    unsigned u = __float_as_uint(f);
    unsigned r = (u + 0x7fffu + ((u >> 16) & 1u)) >> 16;
    return (short)r;
}
// bf16 bits -> f32
__device__ __forceinline__ float bf2f(short s) {
    return __uint_as_float(((unsigned)(unsigned short)s) << 16);
}

// packed pair f32 -> 2 x bf16 in one VALU op: [15:0]=bf16(a), [31:16]=bf16(b)
__device__ __forceinline__ unsigned cvt_pk_bf16(float a, float b) {
    unsigned r;
    asm("v_cvt_pk_bf16_f32 %0, %1, %2" : "=v"(r) : "v"(a), "v"(b));
    return r;
}

// split 8 f32 into hi/lo bf16 short8 fragments (cvt_pk pairs)
__device__ __forceinline__ void split8(const float* v, short8& h8, short8& l8) {
    unsigned hu[4], lu[4];
    #pragma unroll
    for (int p = 0; p < 4; ++p) {
        hu[p] = cvt_pk_bf16(v[2 * p], v[2 * p + 1]);
        const float r0 = v[2 * p]     - __uint_as_float(hu[p] << 16);
        const float r1 = v[2 * p + 1] - __uint_as_float(hu[p] & 0xffff0000u);
        lu[p] = cvt_pk_bf16(r0, r1);
    }
    h8 = __builtin_bit_cast(short8, (uint32x4){hu[0], hu[1], hu[2], hu[3]});
    l8 = __builtin_bit_cast(short8, (uint32x4){lu[0], lu[1], lu[2], lu[3]});
}

// ---------------- counting sort of edges by dst (once per launch) ----------

__global__ __launch_bounds__(256) void sort_zero(unsigned* __restrict__ cnt) {
    const int i = blockIdx.x * 256 + threadIdx.x;
    if (i < N_NODES) cnt[i] = 0u;
}

__global__ __launch_bounds__(256) void sort_hist(const int* __restrict__ dst,
                                                 unsigned* __restrict__ cnt) {
    const int e = blockIdx.x * 256 + threadIdx.x;
    atomicAdd(&cnt[dst[e]], 1u);
}

__global__ __launch_bounds__(256) void sort_psum(const unsigned* __restrict__ cnt,
                                                 unsigned* __restrict__ psum) {
    __shared__ unsigned ws[4];
    const int i = blockIdx.x * 256 + threadIdx.x;
    unsigned v = (i < N_NODES) ? cnt[i] : 0u;
    #pragma unroll
    for (int off = 1; off < 64; off <<= 1) v += __shfl_xor(v, off, 64);
    if ((threadIdx.x & 63) == 0) ws[threadIdx.x >> 6] = v;
    __syncthreads();
    if (threadIdx.x == 0) psum[blockIdx.x] = ws[0] + ws[1] + ws[2] + ws[3];
}

__global__ __launch_bounds__(64) void sort_scan(const unsigned* __restrict__ psum,
                                                unsigned* __restrict__ poff) {
    unsigned carry = 0u;
    const int t = threadIdx.x;
    for (int c = 0; c < NBLK_N; c += 64) {
        const int i = c + t;
        unsigned v = (i < NBLK_N) ? psum[i] : 0u;
        unsigned s = v;
        #pragma unroll
        for (int off = 1; off < 64; off <<= 1) {
            const unsigned u = __shfl_up(s, off, 64);
            if (t >= off) s += u;
        }
        if (i < NBLK_N) poff[i] = carry + s - v;
        carry += __shfl(s, 63, 64);
    }
}

__global__ __launch_bounds__(256) void sort_excl(const unsigned* __restrict__ cnt,
                                                 const unsigned* __restrict__ poff,
                                                 unsigned* __restrict__ cursor) {
    __shared__ unsigned ws[4];
    const int i = blockIdx.x * 256 + threadIdx.x;
    const unsigned v = (i < N_NODES) ? cnt[i] : 0u;
    unsigned s = v;
    #pragma unroll
    for (int off = 1; off < 64; off <<= 1) {
        const unsigned u = __shfl_up(s, off, 64);
        if ((threadIdx.x & 63) >= off) s += u;
    }
    if ((threadIdx.x & 63) == 63) ws[threadIdx.x >> 6] = s;
    __syncthreads();
    unsigned base = poff[blockIdx.x];
    const int w = threadIdx.x >> 6;
    #pragma unroll
    for (int k = 0; k < 3; ++k) if (k < w) base += ws[k];
    if (i < N_NODES) cursor[i] = base + s - v;
}

__global__ __launch_bounds__(256) void sort_scatter(const int* __restrict__ src,
                                                    const int* __restrict__ dst,
                                                    unsigned* __restrict__ cursor,
                                                    int* __restrict__ ssrc,
                                                    int* __restrict__ sdst) {
    const int e = blockIdx.x * 256 + threadIdx.x;
    const int d = dst[e];
    const unsigned p = atomicAdd(&cursor[d], 1u);
    ssrc[p] = src[e];
    sdst[p] = d;
}

// ---------------------------------------------------------------------------

// A = h @ ew1[0:64], B = h @ ew1[64:128] via split-bf16 MFMA (16 nodes/wave);
// also zero h_neigh / x_neigh for this layer. Weight staging parallel.
__global__ __launch_bounds__(256, 2) void node_pre(
    const float* __restrict__ h, const float* __restrict__ ew1,
    float* __restrict__ A, float* __restrict__ B,
    float* __restrict__ h_neigh, float* __restrict__ x_neigh)
{
    __shared__ short8 wHb[16][64];   // hi frags [t*2+kb][lane]; t 0-3 -> A, 4-7 -> B
    __shared__ short8 wLb[16][64];   // lo frags
    const int tid = threadIdx.x;
    const int w = tid >> 6, lane = tid & 63;
    const int col = lane & 15, quad = lane >> 4;
    #pragma unroll
    for (int tt = 0; tt < 2; ++tt) {
        const int t = w * 2 + tt;
        #pragma unroll
        for (int kb = 0; kb < 2; ++kb) {
            short8 hh, ll;
            #pragma unroll
            for (int j = 0; j < 8; ++j) {
                const int k = (t >> 2) * 64 + kb * 32 + quad * 8 + j;
                const float wv = ew1[k * 64 + (t & 3) * 16 + col];
                const short hs = f2bf(wv);
                hh[j] = hs; ll[j] = f2bf(wv - bf2f(hs));
            }
            wHb[t * 2 + kb][lane] = hh;
            wLb[t * 2 + kb][lane] = ll;
        }
    }
    __syncthreads();
    const int nwv = gridDim.x * 4;
    for (int g = blockIdx.x * 4 + w; g < N_NODES / 16; g += nwv) {
        asm volatile("" ::: "memory");
        const int n0 = g * 16;
        // h row of node (col) in A-frag order -> hi/lo fragments
        short8 ah[2], al[2];
        #pragma unroll
        for (int kb = 0; kb < 2; ++kb) {
            const f32x4* hp = (const f32x4*)(h + (size_t)(n0 + col) * 64 + kb * 32 + quad * 8);
            const f32x4 v0 = hp[0], v1 = hp[1];
            const float v[8] = {v0[0], v0[1], v0[2], v0[3], v1[0], v1[1], v1[2], v1[3]};
            split8(v, ah[kb], al[kb]);
        }
        #pragma unroll
        for (int t = 0; t < 8; ++t) {
            f32x4 z = {0.f, 0.f, 0.f, 0.f};
            #pragma unroll
            for (int kb = 0; kb < 2; ++kb) {
                const short8 Bh = wHb[t * 2 + kb][lane];
                const short8 Bl = wLb[t * 2 + kb][lane];
                z = __builtin_amdgcn_mfma_f32_16x16x32_bf16(ah[kb], Bh, z, 0, 0, 0);
                z = __builtin_amdgcn_mfma_f32_16x16x32_bf16(al[kb], Bh, z, 0, 0, 0);
                z = __builtin_amdgcn_mfma_f32_16x16x32_bf16(ah[kb], Bl, z, 0, 0, 0);
            }
            float* dstb = (t < 4) ? A : B;
            const int tt = t & 3;
            #pragma unroll
            for (int r = 0; r < 4; ++r)
                dstb[(size_t)(n0 + quad * 4 + r) * 64 + tt * 16 + col] = z[r];
        }
        // zero h_neigh (coalesced: lane owns 16 consecutive floats) + x_neigh
        {
            f32x4* hz = (f32x4*)(h_neigh + (size_t)n0 * 64 + lane * 16);
            const f32x4 zz = {0.f, 0.f, 0.f, 0.f};
            hz[0] = zz; hz[1] = zz; hz[2] = zz; hz[3] = zz;
        }
        if (lane < 48) x_neigh[n0 * 3 + lane] = 0.0f;
    }
}

// MFMA edge kernel over dst-sorted edges, split-bf16 (hi+lo) for ~f32 accuracy.
// R12's proven residency point: 8-wave blocks, full-width mbuf, ~70.1 KB LDS,
// 2 blocks/CU = 16 waves, grid 512 = single pass. Kept from R13/R14: parallel
// weight staging, per-t GEMM1 write-through, fused GEMM2+c-reduction, rcp xdn.
// (R14's 640-thread/77.5 KB variant lost the 2nd block to reserved LDS.)
__global__ __launch_bounds__(512, 2) void edge_mfma(
    const float* __restrict__ A, const float* __restrict__ B,
    const float* __restrict__ x,
    const int* __restrict__ ssrc, const int* __restrict__ sdst,
    const float* __restrict__ rw,  const float* __restrict__ eb1,
    const float* __restrict__ ew2, const float* __restrict__ eb2,
    const float* __restrict__ cw1, const float* __restrict__ cb1,
    const float* __restrict__ cw2,
    float* __restrict__ h_neigh, float* __restrict__ x_neigh)
{
    __shared__ float rwb[F], eb1b[F];
    __shared__ short8 wEhb[8][64];            // hi(ew2) B-frags [t*2+kb][lane], 8 KB
    __shared__ short8 wElb[8][64];            // lo(ew2) B-frags, 8 KB
    __shared__ short8 wChb[8][64];            // hi(cw1) B-frags, 8 KB
    __shared__ short8 wClb[8][64];            // lo(cw1) B-frags, 8 KB
    __shared__ unsigned mbuf_s[EWAVES][16 * MSTR]; // packed (hi<<16|lo) of m
    __shared__ float cbuf_s[EWAVES][16];
    __shared__ float xbuf_s[EWAVES][48];      // xdn per (edge, comp)
    const int tid = threadIdx.x;
    const int w = tid >> 6, lane = tid & 63;
    const int col = lane & 15, quad = lane >> 4;
    if (tid < 64) rwb[tid] = rw[tid];
    else if (tid < 128) eb1b[tid - 64] = eb1[tid - 64];

    // weight staging: wave w stages unit (t = w>>1, kb = w&1) of all 4 arrays
    {
        const int t = w >> 1, kb = w & 1;
        short8 weh, wch, wel, wcl;
        #pragma unroll
        for (int j = 0; j < 8; ++j) {
            const int k = kb * 32 + quad * 8 + j;
            const float we = ew2[k * 64 + t * 16 + col];
            const float wc = cw1[k * 64 + t * 16 + col];
            const short weh_s = f2bf(we);
            const short wch_s = f2bf(wc);
            weh[j] = weh_s; wch[j] = wch_s;
            wel[j] = f2bf(we - bf2f(weh_s));
            wcl[j] = f2bf(wc - bf2f(wch_s));
        }
        wEhb[t * 2 + kb][lane] = weh;
        wElb[t * 2 + kb][lane] = wel;
        wChb[t * 2 + kb][lane] = wch;
        wClb[t * 2 + kb][lane] = wcl;
    }
    __syncthreads();

    unsigned* mbuf = &mbuf_s[w][0];
    float* cbuf = &cbuf_s[w][0];
    float* xbuf = &xbuf_s[w][0];

    float eb2c[4], cb1c[4], cw2c[4];
    #pragma unroll
    for (int t = 0; t < 4; ++t) {
        eb2c[t] = eb2[t * 16 + col];
        cb1c[t] = cb1[t * 16 + col];
        cw2c[t] = cw2[t * 16 + col];
    }

    const int eL = lane / 3;                 // coord lanes (<48): edge eL, comp cc
    const int cc = lane - eL * 3;
    const int nwv = gridDim.x * EWAVES;
    for (int g = blockIdx.x * EWAVES + w; g < N_EDGES / 16; g += nwv) {
        // compiler barrier: keep LDS-resident weights in LDS (no LICM re-hoist)
        asm volatile("" ::: "memory");

        const int e0 = g * 16;
        const int sv = ssrc[e0 + col];       // edge (col) indices, replicated per quad
        const int dv = sdst[e0 + col];       // sorted: non-decreasing over col

        // gathers directly in A-frag order
        const f32x4* ap = (const f32x4*)(A + (size_t)sv * 64);
        const f32x4* bp = (const f32x4*)(B + (size_t)dv * 64);
        f32x4 ag[4], bg[4];
        ag[0] = ap[quad * 2];     ag[1] = ap[quad * 2 + 1];
        ag[2] = ap[8 + quad * 2]; ag[3] = ap[8 + quad * 2 + 1];
        bg[0] = bp[quad * 2];     bg[1] = bp[quad * 2 + 1];
        bg[2] = bp[8 + quad * 2]; bg[3] = bp[8 + quad * 2 + 1];

        // radial + normalized diff (lanes 0..47 own (edge, comp))
        const int ms = __shfl(sv, eL, 64);
        const int md = __shfl(dv, eL, 64);
        float xs = 0.0f;
        if (lane < 48) xs = x[ms * 3 + cc] - x[md * 3 + cc];
        const float xx = xs * xs;
        const int b3 = col * 3;
        const float radE = __shfl(xx, b3, 64) + __shfl(xx, b3 + 1, 64)
                         + __shfl(xx, b3 + 2, 64);        // radial of edge (col)
        const float rad_e = __shfl(radE, eL, 64);
        const float xdn = xs * __builtin_amdgcn_rcpf(sqrtf(rad_e) + 1e-30f);
        if (lane < 48) xbuf[lane] = xdn;

        // m1 = silu(A[src]+B[dst]+rad*rw+eb1) -> hi/lo A-frags (cvt_pk pairs)
        short8 m1h[2], m1l[2];
        const float* agf = (const float*)ag;
        const float* bgf = (const float*)bg;
        #pragma unroll
        for (int kb = 0; kb < 2; ++kb) {
            float v[8];
            #pragma unroll
            for (int j = 0; j < 8; ++j) {
                const int k = kb * 32 + quad * 8 + j;
                const float pre = agf[kb * 8 + j] + bgf[kb * 8 + j]
                                + radE * rwb[k] + eb1b[k];
                v[j] = silu_f(pre);
            }
            split8(v, m1h[kb], m1l[kb]);
        }

        // GEMM1: m = silu(m1 @ ew2 + eb2) -> packed mbuf (one acc live per t)
        #pragma unroll
        for (int t = 0; t < 4; ++t) {
            f32x4 z = {0.f, 0.f, 0.f, 0.f};
            #pragma unroll
            for (int kb = 0; kb < 2; ++kb) {
                const short8 Eh = wEhb[t * 2 + kb][lane];
                const short8 El = wElb[t * 2 + kb][lane];
                z = __builtin_amdgcn_mfma_f32_16x16x32_bf16(m1h[kb], Eh, z, 0, 0, 0);
                z = __builtin_amdgcn_mfma_f32_16x16x32_bf16(m1l[kb], Eh, z, 0, 0, 0);
                z = __builtin_amdgcn_mfma_f32_16x16x32_bf16(m1h[kb], El, z, 0, 0, 0);
            }
            float v[4];
            #pragma unroll
            for (int r = 0; r < 4; ++r) v[r] = silu_f(z[r] + eb2c[t]);
            #pragma unroll
            for (int p = 0; p < 2; ++p) {
                const unsigned hu = cvt_pk_bf16(v[2 * p], v[2 * p + 1]);
                const float r0 = v[2 * p]     - __uint_as_float(hu << 16);
                const float r1 = v[2 * p + 1] - __uint_as_float(hu & 0xffff0000u);
                const unsigned lu = cvt_pk_bf16(r0, r1);
                const unsigned w0 = (hu << 16) | (lu & 0xffffu);
                const unsigned w1 = (hu & 0xffff0000u) | (lu >> 16);
                mbuf[(quad * 4 + 2 * p)     * MSTR + t * 16 + col] = w0;
                mbuf[(quad * 4 + 2 * p + 1) * MSTR + t * 16 + col] = w1;
            }
        }

        // segmented reduction of m over sorted dst runs: lane = feature.
        // readlane -> SGPR: boundary compares and branches are SCALAR.
        {
            float hacc = 0.0f;
            int prev = __builtin_amdgcn_readlane(dv, 0);
            bool first = true;
            #pragma unroll
            for (int e = 0; e < 16; ++e) {
                const int de = __builtin_amdgcn_readlane(dv, e);
                if (de != prev) {
                    float* p = &h_neigh[(size_t)prev * 64 + lane];
                    if (first) atomicAdd(p, hacc); else *p = hacc;
                    first = false;
                    hacc = 0.0f;
                    prev = de;
                }
                const unsigned u = mbuf[e * MSTR + lane];
                hacc += bf2f((short)(u >> 16)) + bf2f((short)(u & 0xffffu));
            }
            atomicAdd(&h_neigh[(size_t)prev * 64 + lane], hacc);
        }

        // m as hi/lo A-frags (LDS round trip = C/D -> A layout transform)
        short8 mh[2], ml[2];
        #pragma unroll
        for (int kb = 0; kb < 2; ++kb) {
            const unsigned* mp = &mbuf[col * MSTR + kb * 32 + quad * 8];
            short8 h8, l8;
            #pragma unroll
            for (int j = 0; j < 8; ++j) {
                const unsigned u = mp[j];
                h8[j] = (short)(u >> 16);
                l8[j] = (short)(u & 0xffffu);
            }
            mh[kb] = h8; ml[kb] = l8;
        }

        // GEMM2 fused with c-reduction: one accumulator live at a time
        float part[4] = {0.f, 0.f, 0.f, 0.f};
        #pragma unroll
        for (int t = 0; t < 4; ++t) {
            f32x4 z = {0.f, 0.f, 0.f, 0.f};
            #pragma unroll
            for (int kb = 0; kb < 2; ++kb) {
                const short8 Ch = wChb[t * 2 + kb][lane];
                const short8 Cl = wClb[t * 2 + kb][lane];
                z = __builtin_amdgcn_mfma_f32_16x16x32_bf16(mh[kb], Ch, z, 0, 0, 0);
                z = __builtin_amdgcn_mfma_f32_16x16x32_bf16(ml[kb], Ch, z, 0, 0, 0);
                z = __builtin_amdgcn_mfma_f32_16x16x32_bf16(mh[kb], Cl, z, 0, 0, 0);
            }
            #pragma unroll
            for (int r = 0; r < 4; ++r)
                part[r] = fmaf(silu_f(z[r] + cb1c[t]), cw2c[t], part[r]);
        }
        #pragma unroll
        for (int off = 8; off >= 1; off >>= 1)
            #pragma unroll
            for (int r = 0; r < 4; ++r)
                part[r] += __shfl_xor(part[r], off, 64);

        if (col == 0) {
            f32x4 cv = {part[0], part[1], part[2], part[3]};
            *(f32x4*)&cbuf[quad * 4] = cv;
        }

        // segmented x_neigh scatter: 3 lanes, scalar run boundaries (readlane)
        if (lane < 3) {
            float xacc = 0.0f;
            int prev = __builtin_amdgcn_readlane(dv, 0);
            bool first = true;
            #pragma unroll
            for (int e = 0; e < 16; ++e) {
                const int de = __builtin_amdgcn_readlane(dv, e);
                if (de != prev) {
                    float* p = &x_neigh[(size_t)prev * 3 + lane];
                    if (first) atomicAdd(p, xacc); else *p = xacc;
                    first = false;
                    xacc = 0.0f;
                    prev = de;
                }
                xacc = fmaf(cbuf[e], xbuf[e * 3 + lane], xacc);
            }
            atomicAdd(&x_neigh[(size_t)prev * 3 + lane], xacc);
        }
    }
}

// h_new = silu([h,h_neigh] @ nw1 + nb1) @ nw2 + nb2;  x_new = x + x_neigh.
// Split-bf16 MFMA, 16 nodes/wave; weight staging parallel across 4 waves.
__global__ __launch_bounds__(256, 2) void node_post(
    const float* __restrict__ h, const float* __restrict__ hng,
    const float* __restrict__ nw1, const float* __restrict__ nb1,
    const float* __restrict__ nw2, const float* __restrict__ nb2,
    const float* __restrict__ x_in, const float* __restrict__ xng,
    float* __restrict__ h_out, float* __restrict__ x_out)
{
    __shared__ short8 w1h[16][64], w1l[16][64];  // nw1 frags [t*4+kb][lane], 32 KB
    __shared__ short8 w2h[8][64],  w2l[8][64];   // nw2 frags [t*2+kb][lane], 16 KB
    __shared__ unsigned mbuf_s[4][16 * MSTR];    // per-wave packed intermediate
    const int tid = threadIdx.x;
    const int w = tid >> 6, lane = tid & 63;
    const int col = lane & 15, quad = lane >> 4;
    {
        const int t = w;  // wave w stages t = w for both weight sets
        #pragma unroll
        for (int kb = 0; kb < 4; ++kb) {
            short8 hh, ll;
            #pragma unroll
            for (int j = 0; j < 8; ++j) {
                const int k = kb * 32 + quad * 8 + j;
                const float wv = nw1[k * 64 + t * 16 + col];
                const short hs = f2bf(wv);
                hh[j] = hs; ll[j] = f2bf(wv - bf2f(hs));
            }
            w1h[t * 4 + kb][lane] = hh;
            w1l[t * 4 + kb][lane] = ll;
        }
        #pragma unroll
        for (int kb = 0; kb < 2; ++kb) {
            short8 hh, ll;
            #pragma unroll
            for (int j = 0; j < 8; ++j) {
                const int k = kb * 32 + quad * 8 + j;
                const float wv = nw2[k * 64 + t * 16 + col];
                const short hs = f2bf(wv);
                hh[j] = hs; ll[j] = f2bf(wv - bf2f(hs));
            }
            w2h[t * 2 + kb][lane] = hh;
            w2l[t * 2 + kb][lane] = ll;
        }
    }
    __syncthreads();

    unsigned* mbuf = &mbuf_s[w][0];
    float b1c[4], b2c[4];
    #pragma unroll
    for (int t = 0; t < 4; ++t) {
        b1c[t] = nb1[t * 16 + col];
        b2c[t] = nb2[t * 16 + col];
    }

    const int nwv = gridDim.x * 4;
    for (int g = blockIdx.x * 4 + w; g < N_NODES / 16; g += nwv) {
        asm volatile("" ::: "memory");
        const int n0 = g * 16;
        // A-frags over K=128: kb 0,1 from h row; kb 2,3 from hng row
        short8 ah[4], al[4];
        #pragma unroll
        for (int kb = 0; kb < 4; ++kb) {
            const float* base = (kb < 2) ? h : hng;
            const f32x4* hp = (const f32x4*)(base + (size_t)(n0 + col) * 64
                                             + (kb & 1) * 32 + quad * 8);
            const f32x4 v0 = hp[0], v1 = hp[1];
            const float v[8] = {v0[0], v0[1], v0[2], v0[3], v1[0], v1[1], v1[2], v1[3]};
            split8(v, ah[kb], al[kb]);
        }

        // GEMM1: t_pre = [h,hng] @ nw1 + nb1; silu -> packed mbuf
        #pragma unroll
        for (int t = 0; t < 4; ++t) {
            f32x4 z = {b1c[t], b1c[t], b1c[t], b1c[t]};
            #pragma unroll
            for (int kb = 0; kb < 4; ++kb) {
                const short8 Bh = w1h[t * 4 + kb][lane];
                const short8 Bl = w1l[t * 4 + kb][lane];
                z = __builtin_amdgcn_mfma_f32_16x16x32_bf16(ah[kb], Bh, z, 0, 0, 0);
                z = __builtin_amdgcn_mfma_f32_16x16x32_bf16(al[kb], Bh, z, 0, 0, 0);
                z = __builtin_amdgcn_mfma_f32_16x16x32_bf16(ah[kb], Bl, z, 0, 0, 0);
            }
            float v[4];
            #pragma unroll
            for (int r = 0; r < 4; ++r) v[r] = silu_f(z[r]);
            #pragma unroll
            for (int p = 0; p < 2; ++p) {
                const unsigned hu = cvt_pk_bf16(v[2 * p], v[2 * p + 1]);
                const float r0 = v[2 * p]     - __uint_as_float(hu << 16);
                const float r1 = v[2 * p + 1] - __uint_as_float(hu & 0xffff0000u);
                const unsigned lu = cvt_pk_bf16(r0, r1);
                const unsigned w0 = (hu << 16) | (lu & 0xffffu);
                const unsigned w1 = (hu & 0xffff0000u) | (lu >> 16);
                mbuf[(quad * 4 + 2 * p)     * MSTR + t * 16 + col] = w0;
                mbuf[(quad * 4 + 2 * p + 1) * MSTR + t * 16 + col] = w1;
            }
        }

        // reload intermediate as hi/lo A-frags (C/D -> A layout transform)
        short8 mh[2], ml[2];
        #pragma unroll
        for (int kb = 0; kb < 2; ++kb) {
            const unsigned* mp = &mbuf[col * MSTR + kb * 32 + quad * 8];
            short8 h8, l8;
            #pragma unroll
            for (int j = 0; j < 8; ++j) {
                const unsigned u = mp[j];
                h8[j] = (short)(u >> 16);
                l8[j] = (short)(u & 0xffffu);
            }
            mh[kb] = h8; ml[kb] = l8;
        }

        // GEMM2: h_new = t @ nw2 + nb2
        #pragma unroll
        for (int t = 0; t < 4; ++t) {
            f32x4 z = {b2c[t], b2c[t], b2c[t], b2c[t]};
            #pragma unroll
            for (int kb = 0; kb < 2; ++kb) {
                const short8 Bh = w2h[t * 2 + kb][lane];
                const short8 Bl = w2l[t * 2 + kb][lane];
                z = __builtin_amdgcn_mfma_f32_16x16x32_bf16(mh[kb], Bh, z, 0, 0, 0);
                z = __builtin_amdgcn_mfma_f32_16x16x32_bf16(ml[kb], Bh, z, 0, 0, 0);
                z = __builtin_amdgcn_mfma_f32_16x16x32_bf16(mh[kb], Bl, z, 0, 0, 0);
            }
            #pragma unroll
            for (int r = 0; r < 4; ++r)
                h_out[(size_t)(n0 + quad * 4 + r) * 64 + t * 16 + col] = z[r];
        }

        // x update for these 16 nodes (48 components)
        if (lane < 48) x_out[n0 * 3 + lane] = x_in[n0 * 3 + lane] + xng[n0 * 3 + lane];
    }
}

// final layer: only x_out = x + x_neigh (h_new of layer 3 is never read)
__global__ __launch_bounds__(256) void x_finish(
    const float* __restrict__ x_in, const float* __restrict__ xng,
    float* __restrict__ x_out)
{
    const int i = blockIdx.x * 256 + threadIdx.x;
    if (i < N_NODES * 3) x_out[i] = x_in[i] + xng[i];
}

extern "C" void kernel_launch(void* const* d_in, const int* in_sizes, int n_in,
                              void* d_out, int out_size, void* d_ws, size_t ws_size,
                              hipStream_t stream) {
    const float* h_in0 = (const float*)d_in[0];
    const float* x_in0 = (const float*)d_in[1];
    const int*   src   = (const int*)d_in[2];
    const int*   dst   = (const int*)d_in[3];
    const float* ew1   = (const float*)d_in[4];
    const float* eb1   = (const float*)d_in[5];
    const float* ew2   = (const float*)d_in[6];
    const float* eb2   = (const float*)d_in[7];
    const float* nw1   = (const float*)d_in[8];
    const float* nb1   = (const float*)d_in[9];
    const float* nw2   = (const float*)d_in[10];
    const float* nb2   = (const float*)d_in[11];
    const float* cw1   = (const float*)d_in[12];
    const float* cb1   = (const float*)d_in[13];
    const float* cw2   = (const float*)d_in[14];
    float* out = (float*)d_out;

    const size_t NF = (size_t)N_NODES * F;
    float* A   = (float*)d_ws;       // [N,64]
    float* Bm  = A + NF;             // [N,64]
    float* hng = Bm + NF;            // h_neigh [N,64]
    float* h0  = hng + NF;           // h ping  [N,64]
    float* h1  = h0 + NF;            // h pong  [N,64]
    float* xw  = h1 + NF;            // x       [N,3]
    float* xng = xw + (size_t)N_NODES * 3;  // x_neigh [N,3]
    unsigned* cnt    = (unsigned*)(xng + (size_t)N_NODES * 3);  // [N]
    unsigned* cursor = cnt + N_NODES;                           // [N]
    unsigned* psum   = cursor + N_NODES;                        // [NBLK_N]
    unsigned* poff   = psum + NBLK_N;                           // [NBLK_N]
    int* ssrc = (int*)(poff + NBLK_N);                          // [E]
    int* sdst = ssrc + N_EDGES;                                 // [E]

    // counting sort of edges by dst — once per launch, shared by all 4 layers
    sort_zero<<<NBLK_N, 256, 0, stream>>>(cnt);
    sort_hist<<<NBLK_E, 256, 0, stream>>>(dst, cnt);
    sort_psum<<<NBLK_N, 256, 0, stream>>>(cnt, psum);
    sort_scan<<<1, 64, 0, stream>>>(psum, poff);
    sort_excl<<<NBLK_N, 256, 0, stream>>>(cnt, poff, cursor);
    sort_scatter<<<NBLK_E, 256, 0, stream>>>(src, dst, cursor, ssrc, sdst);

    for (int d = 0; d < 4; ++d) {
        const float* hcur = (d == 0) ? h_in0 : ((d & 1) ? h0 : h1);
        float* hout = (d & 1) ? h1 : h0;
        const float* xcur = (d == 0) ? x_in0 : xw;
        node_pre<<<512, 256, 0, stream>>>(hcur, ew1 + (size_t)d * 129 * F,
                                          A, Bm, hng, xng);
        edge_mfma<<<512, 512, 0, stream>>>(A, Bm, xcur, ssrc, sdst,
            ew1 + (size_t)d * 129 * F + 128 * F, eb1 + d * F,
            ew2 + (size_t)d * F * F, eb2 + d * F,
            cw1 + (size_t)d * F * F, cb1 + d * F, cw2 + d * F,
            hng, xng);
        if (d < 3) {
            node_post<<<512, 256, 0, stream>>>(hcur, hng,
                nw1 + (size_t)d * 2 * F * F, nb1 + d * F,
                nw2 + (size_t)d * F * F, nb2 + d * F,
                xcur, xng, hout, xw);
        } else {
            x_finish<<<(N_NODES * 3 + 255) / 256, 256, 0, stream>>>(xcur, xng, out);
        }
    }
}